// Round 5
// baseline (116.820 us; speedup 1.0000x reference)
//
#include <hip/hip_runtime.h>

#define NB 4
#define NC 32
#define NH 32
#define NW 32
#define KK 288                   // 32*3*3 patch length
#define PLANE (NB*NC*NH*NW)      // 131072 elements per plane
#define CQ 8                     // channels per block (quarter split)

__device__ __forceinline__ float s3(float v) { return sqrtf(sqrtf(sqrtf(v))); }

// Zero-mean weight rows; write padded float4 layout [co][c][r] = {w(r,0),w(r,1),w(r,2),pad}.
__global__ __launch_bounds__(256) void prep_weights_k(
        const float* __restrict__ w1, const float* __restrict__ w2,
        float* __restrict__ wf1, float* __restrict__ wf2)
{
    const int row = blockIdx.x;                   // 0..63
    const float* src = (row < NC) ? w1 : w2;
    float* dst = (row < NC) ? wf1 : wf2;
    const int co = row & (NC - 1);
    const int tid = threadIdx.x;
    __shared__ float red[256];
    const float a = src[co*KK + tid];                              // tid < 256 < 288
    const float b = (tid + 256 < KK) ? src[co*KK + tid + 256] : 0.0f;
    red[tid] = a + b;
    __syncthreads();
    for (int s = 128; s > 0; s >>= 1) {
        if (tid < s) red[tid] += red[tid + s];
        __syncthreads();
    }
    const float mean = red[0] * (1.0f / (float)KK);
    {
        const int e = tid, c = e / 9, r9 = e - c*9, r = r9 / 3, kw = r9 - r*3;
        dst[co*384 + ((c*3 + r) << 2) + kw] = a - mean;
    }
    if (tid + 256 < KK) {
        const int e = tid + 256, c = e / 9, r9 = e - c*9, r = r9 / 3, kw = r9 - r*3;
        dst[co*384 + ((c*3 + r) << 2) + kw] = b - mean;
    }
}

// Quarter-channel norm-dist conv, 2 outputs (co, co+8) per thread.
// Block = 32(w) x 8(ty). Grid = (h=32, cog*4+q=8, b=4) = 1024 blocks.
// STAGE1: stages x/l/u. STAGE2: stages s3(sum of conv1's 4 partials).
// Writes partial (pre-root) sums at [q*PLANE + o].
template<bool STAGE2>
__global__ __launch_bounds__(256, 4) void normdist_conv_k(
    const float* __restrict__ sy,     // stage1: x | stage2: conv1 Y partials [4][PLANE]
    const float* __restrict__ sl,
    const float* __restrict__ su,
    const float* __restrict__ wf,     // prepped weights, float4 [co][c][r]
    float* __restrict__ pY, float* __restrict__ pL, float* __restrict__ pU)
{
    const int h   = blockIdx.x;
    const int cog = blockIdx.y >> 2;          // 0..1 : co-group of 16
    const int q   = blockIdx.y & 3;           // 0..3 : input-channel quarter
    const int ch0 = q * CQ;
    const int b   = blockIdx.z;
    const int tx  = threadIdx.x;
    const int ty  = threadIdx.y;
    const int tid = ty * 32 + tx;

    // Patch halo, xlu-interleaved: [c<8][r<3][col<34] float4 (w unused). 13056 B.
    __shared__ float4 sP[CQ*3*34];

    for (int i = tid; i < CQ*3*34; i += 256) {
        const int c   = i / 102;
        const int rem = i - c*102;
        const int r   = rem / 34;
        const int col = rem - r*34;
        const int gh  = h + r - 1;
        const int gw  = col - 1;
        float vx = 0.0f, vl = 0.0f, vu = 0.0f;
        if ((unsigned)gh < NH && (unsigned)gw < NW) {
            const int g = ((b*NC + ch0 + c)*NH + gh)*NW + gw;
            if (STAGE2) {   // combine conv1 quarters + eighth-root (relu no-op: >= 0)
                vx = s3(sy[g] + sy[PLANE + g] + sy[2*PLANE + g] + sy[3*PLANE + g]);
                vl = s3(sl[g] + sl[PLANE + g] + sl[2*PLANE + g] + sl[3*PLANE + g]);
                vu = s3(su[g] + su[PLANE + g] + su[2*PLANE + g] + su[3*PLANE + g]);
            } else {
                vx = sy[g]; vl = sl[g]; vu = su[g];
            }
        }
        sP[i] = make_float4(vx, vl, vu, 0.0f);
    }
    __syncthreads();

    const int co0 = cog*16 + ty;              // this thread's two output channels
    const int co1 = co0 + 8;
    const float4* wb0 = (const float4*)wf + (co0*NC + ch0)*3;
    const float4* wb1 = (const float4*)wf + (co1*NC + ch0)*3;

    float y0 = 0.0f, l0 = 0.0f, u0 = 0.0f;
    float y1 = 0.0f, l1 = 0.0f, u1 = 0.0f;

    // 14 VALU per tap: y(4) + shared subs(2) + dl(max3,2 mul,fma=4) + du(max|.|,2 mul,fma=4)
    auto tap = [](float wv, float4 p, float& aY, float& aL, float& aU) {
        const float d  = p.x - wv;
        const float d2 = d*d, d4 = d2*d2;
        aY = fmaf(d4, d4, aY);
        const float a  = p.y - wv;
        const float nb = wv - p.z;
        const float m  = fmaxf(fmaxf(a, nb), 0.0f);      // -> v_max3_f32
        const float m2 = m*m, m4 = m2*m2;
        aL = fmaf(m4, m4, aL);
        const float mm  = fmaxf(fabsf(a), fabsf(nb));    // -> v_max_f32 |a|,|b|
        const float mm2 = mm*mm, mm4 = mm2*mm2;
        aU = fmaf(mm4, mm4, aU);
    };

    #pragma unroll 2
    for (int c = 0; c < CQ; ++c) {
        const float4 wA0 = wb0[c*3 + 0], wA1 = wb0[c*3 + 1], wA2 = wb0[c*3 + 2];
        const float4 wB0 = wb1[c*3 + 0], wB1 = wb1[c*3 + 1], wB2 = wb1[c*3 + 2];
        const int pb = c*102 + tx;
        const float4 p00 = sP[pb +  0], p01 = sP[pb +  1], p02 = sP[pb +  2];
        const float4 p10 = sP[pb + 34], p11 = sP[pb + 35], p12 = sP[pb + 36];
        const float4 p20 = sP[pb + 68], p21 = sP[pb + 69], p22 = sP[pb + 70];
        tap(wA0.x, p00, y0,l0,u0); tap(wA0.y, p01, y0,l0,u0); tap(wA0.z, p02, y0,l0,u0);
        tap(wA1.x, p10, y0,l0,u0); tap(wA1.y, p11, y0,l0,u0); tap(wA1.z, p12, y0,l0,u0);
        tap(wA2.x, p20, y0,l0,u0); tap(wA2.y, p21, y0,l0,u0); tap(wA2.z, p22, y0,l0,u0);
        tap(wB0.x, p00, y1,l1,u1); tap(wB0.y, p01, y1,l1,u1); tap(wB0.z, p02, y1,l1,u1);
        tap(wB1.x, p10, y1,l1,u1); tap(wB1.y, p11, y1,l1,u1); tap(wB1.z, p12, y1,l1,u1);
        tap(wB2.x, p20, y1,l1,u1); tap(wB2.y, p21, y1,l1,u1); tap(wB2.z, p22, y1,l1,u1);
    }

    const int o0 = ((b*NC + co0)*NH + h)*NW + tx;
    const int o1 = ((b*NC + co1)*NH + h)*NW + tx;
    pY[q*PLANE + o0] = y0;  pL[q*PLANE + o0] = l0;  pU[q*PLANE + o0] = u0;
    pY[q*PLANE + o1] = y1;  pL[q*PLANE + o1] = l1;  pU[q*PLANE + o1] = u1;
}

// Combine conv2 quarters, eighth-root, add residual, relu, write out.
__global__ __launch_bounds__(256) void epilogue_k(
    const float* __restrict__ pY, const float* __restrict__ pL, const float* __restrict__ pU,
    const float* __restrict__ x,  const float* __restrict__ l,  const float* __restrict__ u,
    float* __restrict__ out)
{
    const int o = blockIdx.x*256 + threadIdx.x;
    const float y  = s3(pY[o] + pY[PLANE + o] + pY[2*PLANE + o] + pY[3*PLANE + o]);
    const float dl = s3(pL[o] + pL[PLANE + o] + pL[2*PLANE + o] + pL[3*PLANE + o]);
    const float du = s3(pU[o] + pU[PLANE + o] + pU[2*PLANE + o] + pU[3*PLANE + o]);
    out[o]           = fmaxf(y  + x[o], 0.0f);
    out[PLANE + o]   = fmaxf(dl + l[o], 0.0f);
    out[2*PLANE + o] = fmaxf(du + u[o], 0.0f);
}

extern "C" void kernel_launch(void* const* d_in, const int* in_sizes, int n_in,
                              void* d_out, int out_size, void* d_ws, size_t ws_size,
                              hipStream_t stream)
{
    const float* x  = (const float*)d_in[0];
    const float* l  = (const float*)d_in[1];
    const float* u  = (const float*)d_in[2];
    const float* w1 = (const float*)d_in[3];
    const float* w2 = (const float*)d_in[4];
    float* ws  = (float*)d_ws;
    float* wf1 = ws;                        // 12288 floats (padded float4 layout)
    float* wf2 = wf1 + 12288;
    float* p1Y = wf2 + 12288;               // conv1 partials: [4][PLANE] each
    float* p1L = p1Y + 4*PLANE;
    float* p1U = p1L + 4*PLANE;
    float* p2Y = p1U + 4*PLANE;             // conv2 partials
    float* p2L = p2Y + 4*PLANE;
    float* p2U = p2L + 4*PLANE;
    float* out = (float*)d_out;

    prep_weights_k<<<64, 256, 0, stream>>>(w1, w2, wf1, wf2);

    dim3 blk(32, 8);
    dim3 grd(NH, 8, NB);                    // h, cog*4+q, b  -> 1024 blocks
    normdist_conv_k<false><<<grd, blk, 0, stream>>>(x, l, u, wf1, p1Y, p1L, p1U);
    normdist_conv_k<true ><<<grd, blk, 0, stream>>>(p1Y, p1L, p1U, wf2, p2Y, p2L, p2U);
    epilogue_k<<<PLANE/256, 256, 0, stream>>>(p2Y, p2L, p2U, x, l, u, out);
}